// Round 1
// baseline (403.570 us; speedup 1.0000x reference)
//
#include <hip/hip_runtime.h>
#include <hip/hip_bf16.h>

typedef __attribute__((ext_vector_type(4))) float f32x4;
typedef __attribute__((ext_vector_type(8))) short bf16x8;
typedef __attribute__((ext_vector_type(4))) int int4v;

#define LCH 4        // timesteps emitted per chunk
#define WARM 16      // warmup steps per chunk
#define NSTEP (WARM + LCH)

// ---------------------------------------------------------------------------
// prep_Pt: P transposed + tiled for coalesced MFMA B-fragment loads.
// Pt[(nt*32+kc)*512 + nw*32 + kw] = exp(trans[(kc*32+kw)*1024 + nt*16+nw])
//   nt = n>>4 (64 col-tiles), kc = k>>5 (32 k-chunks), nw = n&15, kw = k&31
// B-frag for wave at (nt,kc): lane l reads 16B at nw=(l&15), kw=(l>>4)*8 -> wave
// covers 1KB contiguous.
// ---------------------------------------------------------------------------
__global__ void prep_Pt(const float* __restrict__ trans,
                        __hip_bfloat16* __restrict__ Pt) {
  __shared__ float l[4 * 544];  // [kcl][kw*17+nw], padded vs bank conflicts
  const int nt = blockIdx.x >> 3;
  const int kc0 = (blockIdx.x & 7) << 2;
  for (int e = threadIdx.x; e < 2048; e += 256) {
    const int kcl = e >> 9, kw = (e >> 4) & 31, nw = e & 15;
    l[kcl * 544 + kw * 17 + nw] =
        __expf(trans[(size_t)((kc0 + kcl) * 32 + kw) * 1024 + nt * 16 + nw]);
  }
  __syncthreads();
  for (int o = threadIdx.x; o < 2048; o += 256) {
    const int kw = o & 31, nw = (o >> 5) & 15, kcl = o >> 9;
    Pt[(size_t)(nt * 32 + kc0 + kcl) * 512 + nw * 32 + kw] =
        __float2bfloat16(l[kcl * 544 + kw * 17 + nw]);
  }
}

// ---------------------------------------------------------------------------
// prep_Ex: Ex[t][j] = exp(emit[j][xs[t]])  (f32, [T][1024], coalesced writes)
// ---------------------------------------------------------------------------
__global__ void prep_Ex(const float* __restrict__ emit, const int* __restrict__ xs,
                        float* __restrict__ Ex, int V) {
  const int t = blockIdx.x;
  const int x = xs[t];
  const float* col = emit + x;
  for (int j = threadIdx.x; j < 1024; j += 256)
    Ex[(size_t)t * 1024 + j] = __expf(col[(size_t)j * V]);
}

// ---------------------------------------------------------------------------
// prep_A0: row 0 = exact alpha_0 (unnormalized) = exp(start)*E_0; rows>=1 = 1.0
// ---------------------------------------------------------------------------
__global__ void prep_A0(const float* __restrict__ start, const float* __restrict__ Ex,
                        __hip_bfloat16* __restrict__ A0) {
  const int idx = blockIdx.x * 256 + threadIdx.x;
  const int r = idx >> 10, j = idx & 1023;
  const float v = (r == 0) ? __expf(start[j]) * Ex[j] : 1.0f;
  A0[idx] = __float2bfloat16(v);
}

// ---------------------------------------------------------------------------
// stage one 128-k block of the WG's 64 A-rows into LDS.
// LDS layout [q][row][32 kw] (rows are 64B -> ds_read frags hit 2-way banks = free)
// ---------------------------------------------------------------------------
__device__ __forceinline__ void stage_rows(const __hip_bfloat16* __restrict__ Acur,
                                           __hip_bfloat16 (*buf)[64][32],
                                           int m0, int kb, int w, int l) {
#pragma unroll
  for (int q = 0; q < 4; ++q) {
    const __hip_bfloat16* srcp = Acur + (size_t)(m0 + w * 16 + (l >> 2)) * 1024 +
                                 (kb * 4 + q) * 32 + (l & 3) * 8;
    const int4v v = *(const int4v*)srcp;
    *(int4v*)&buf[q][w * 16 + (l >> 2)][(l & 3) * 8] = v;
  }
}

// ---------------------------------------------------------------------------
// one recurrence step for all C chunk-rows:  A_next = (A_cur @ P) .* E  * 2^15
// grid (16 ngroups, C/64 mgroups), 256 threads (4 waves).
// WG tile: 64 rows x 64 cols; wave w owns col-tile ntw = ng*4+w (16 cols),
// 4 row-tiles of 16. Row r == chunk c; its time at step s:
//   c>=1: t = c*LCH - 1 - WARM + s  (clamped to >=0 during early warmup)
//   c==0: frozen at exact alpha_0 for s<=WARM, then t = s-WARM.
// Row sums recorded (per-ngroup partials) for s >= WARM.
// ---------------------------------------------------------------------------
__global__ __launch_bounds__(256) void hmm_step(
    const __hip_bfloat16* __restrict__ Acur, __hip_bfloat16* __restrict__ Anext,
    const __hip_bfloat16* __restrict__ Pt, const float* __restrict__ Ex,
    float* __restrict__ Spart, int s) {
  __shared__ __align__(16) __hip_bfloat16 Astage[2][4][64][32];
  __shared__ float sred[4][64];
  const int tid = threadIdx.x;
  const int w = tid >> 6;
  const int l = tid & 63;
  const int ng = blockIdx.x;
  const int mg = blockIdx.y;
  const int m0 = mg << 6;
  const int n0 = ng << 6;
  const int ntw = (ng << 2) + w;

  f32x4 acc[4];
#pragma unroll
  for (int rt = 0; rt < 4; ++rt)
#pragma unroll
    for (int jj = 0; jj < 4; ++jj) acc[rt][jj] = 0.0f;

  stage_rows(Acur, Astage[0], m0, 0, w, l);
  __syncthreads();

  for (int kb = 0; kb < 8; ++kb) {
    const int buf = kb & 1;
    if (kb < 7) stage_rows(Acur, Astage[buf ^ 1], m0, kb + 1, w, l);
#pragma unroll
    for (int q = 0; q < 4; ++q) {
      const int kc = (kb << 2) + q;
      const bf16x8 bfrag = *(const bf16x8*)(Pt + (size_t)(ntw * 32 + kc) * 512 +
                                            (l & 15) * 32 + (l >> 4) * 8);
#pragma unroll
      for (int rt = 0; rt < 4; ++rt) {
        const bf16x8 afrag =
            *(const bf16x8*)&Astage[buf][q][rt * 16 + (l & 15)][(l >> 4) * 8];
        acc[rt] = __builtin_amdgcn_mfma_f32_16x16x32_bf16(afrag, bfrag, acc[rt], 0, 0, 0);
      }
    }
    __syncthreads();
  }

  // elementwise: emission scale, 2^15 rescale, bf16 writeback, row partial sums
  const int n = n0 + (w << 4) + (l & 15);
#pragma unroll
  for (int rt = 0; rt < 4; ++rt) {
#pragma unroll
    for (int j = 0; j < 4; ++j) {
      const int rl = rt * 16 + ((l >> 4) << 2) + j;
      const int r = m0 + rl;
      int t = (r == 0) ? (s - WARM) : (r * LCH - 1 - WARM + s);
      if (t < 0) t = 0;
      float outv;
      if ((r > 0) || (s > WARM))
        outv = acc[rt][j] * Ex[(size_t)t * 1024 + n] * 32768.0f;
      else
        outv = __bfloat162float(Acur[n]);  // chunk 0 frozen during warmup
      Anext[(size_t)r * 1024 + n] = __float2bfloat16(outv);
      float ssum = outv;
      ssum += __shfl_xor(ssum, 1);
      ssum += __shfl_xor(ssum, 2);
      ssum += __shfl_xor(ssum, 4);
      ssum += __shfl_xor(ssum, 8);
      if ((l & 15) == 0) sred[w][rl] = ssum;
    }
  }
  __syncthreads();
  if (s >= WARM && tid < 64) {
    const float tot = sred[0][tid] + sred[1][tid] + sred[2][tid] + sred[3][tid];
    Spart[((size_t)(m0 + tid) * (LCH + 1) + (s - WARM)) * 16 + ng] = tot;
  }
}

// ---------------------------------------------------------------------------
// final: Z_t from log-ratios of consecutive scaled sums.
// ---------------------------------------------------------------------------
__global__ void hmm_final(const float* __restrict__ Spart, float* __restrict__ out,
                          int T) {
  const int t = blockIdx.x * 256 + threadIdx.x;
  if (t >= T) return;
  const float C15 = 10.397207708399179f;  // 15*ln2
  auto S = [&](int c, int k) {
    const float* p = Spart + ((size_t)c * (LCH + 1) + k) * 16;
    float acc = 0.f;
#pragma unroll
    for (int g = 0; g < 16; ++g) acc += p[g];
    return acc;
  };
  float z;
  if (t == 0)
    z = logf(S(0, 0));
  else if (t < LCH)
    z = logf(S(0, t)) - logf(S(0, t - 1)) - C15;
  else {
    const int c = t >> 2, e = t & 3;
    z = logf(S(c, e + 1)) - logf(S(c, e)) - C15;
  }
  out[t] = z;
}

// ---------------------------------------------------------------------------
extern "C" void kernel_launch(void* const* d_in, const int* in_sizes, int n_in,
                              void* d_out, int out_size, void* d_ws, size_t ws_size,
                              hipStream_t stream) {
  const int* xs = (const int*)d_in[0];
  const float* start = (const float*)d_in[1];
  const float* trans = (const float*)d_in[2];
  const float* emit = (const float*)d_in[3];
  float* out = (float*)d_out;
  const int T = out_size;            // 4096
  const int V = in_sizes[3] >> 10;   // 32000
  const int C = T / LCH;             // 1024 chunks

  char* ws = (char*)d_ws;
  __hip_bfloat16* Pt = (__hip_bfloat16*)ws;                  // 2 MB
  float* Ex          = (float*)(ws + (2u << 20));            // 16 MB
  __hip_bfloat16* A0 = (__hip_bfloat16*)(ws + (18u << 20));  // 2 MB
  __hip_bfloat16* A1 = (__hip_bfloat16*)(ws + (20u << 20));  // 2 MB
  float* Spart       = (float*)(ws + (22u << 20));           // 320 KB

  prep_Pt<<<dim3(512), dim3(256), 0, stream>>>(trans, Pt);
  prep_Ex<<<dim3(T), dim3(256), 0, stream>>>(emit, xs, Ex, V);
  prep_A0<<<dim3(C * 4), dim3(256), 0, stream>>>(start, Ex, A0);
  for (int s = 1; s <= NSTEP; ++s) {
    const __hip_bfloat16* ain = (s & 1) ? A0 : A1;
    __hip_bfloat16* aout = (s & 1) ? A1 : A0;
    hmm_step<<<dim3(16, C >> 6), dim3(256), 0, stream>>>(ain, aout, Pt, Ex, Spart, s);
  }
  hmm_final<<<dim3((T + 255) / 256), dim3(256), 0, stream>>>(Spart, out, T);
}

// Round 2
// 224.322 us; speedup vs baseline: 1.7991x; 1.7991x over previous
//
#include <hip/hip_runtime.h>
#include <hip/hip_bf16.h>

typedef __attribute__((ext_vector_type(4))) float f32x4;
typedef __attribute__((ext_vector_type(8))) short bf16x8;
typedef __attribute__((ext_vector_type(4))) int int4v;

#define LCH 4        // timesteps emitted per chunk
#define WARM 6       // warmup steps per chunk (mixing ~0.009/step -> 1e-12 rel err)
#define NSTEP (WARM + LCH)
#define ROWS 32      // chunk-rows per workgroup (512 WGs -> 2 WG/CU)

// ---------------------------------------------------------------------------
// prep_Pt: P transposed + tiled for coalesced MFMA B-fragment loads.
// Pt[(nt*32+kc)*512 + nw*32 + kw] = exp(trans[(kc*32+kw)*1024 + nt*16+nw])
// ---------------------------------------------------------------------------
__global__ void prep_Pt(const float* __restrict__ trans,
                        __hip_bfloat16* __restrict__ Pt) {
  __shared__ float l[4 * 544];  // [kcl][kw*17+nw], padded vs bank conflicts
  const int nt = blockIdx.x >> 3;
  const int kc0 = (blockIdx.x & 7) << 2;
  for (int e = threadIdx.x; e < 2048; e += 256) {
    const int kcl = e >> 9, kw = (e >> 4) & 31, nw = e & 15;
    l[kcl * 544 + kw * 17 + nw] =
        __expf(trans[(size_t)((kc0 + kcl) * 32 + kw) * 1024 + nt * 16 + nw]);
  }
  __syncthreads();
  for (int o = threadIdx.x; o < 2048; o += 256) {
    const int kw = o & 31, nw = (o >> 5) & 15, kcl = o >> 9;
    Pt[(size_t)(nt * 32 + kc0 + kcl) * 512 + nw * 32 + kw] =
        __float2bfloat16(l[kcl * 544 + kw * 17 + nw]);
  }
}

// ---------------------------------------------------------------------------
// prep_gather: ExT[j][t] = exp(emit[j][xs[t]]). One block per state j: all
// gathers land in row j's 125 KB window (L2-resident -> each line fetched
// once ~= 111 MB HBM total). Writes fully coalesced.
// ---------------------------------------------------------------------------
__global__ void prep_gather(const float* __restrict__ emit,
                            const int* __restrict__ xs,
                            float* __restrict__ ExT, int V, int T) {
  const int j = blockIdx.x;
  const float* row = emit + (size_t)j * V;
  float* orow = ExT + (size_t)j * T;
  for (int t = threadIdx.x; t < T; t += 256) orow[t] = __expf(row[xs[t]]);
}

// ---------------------------------------------------------------------------
// prep_tr: Ex[t][j] = ExT[j][t] via 64x64 LDS tiles, both sides coalesced.
// ---------------------------------------------------------------------------
__global__ void prep_tr(const float* __restrict__ ExT, float* __restrict__ Ex,
                        int T) {
  __shared__ float tile[64][65];
  const int tb = blockIdx.x << 6, jb = blockIdx.y << 6;
  for (int i = threadIdx.x; i < 4096; i += 256) {
    const int jj = i >> 6, tt = i & 63;
    tile[jj][tt] = ExT[(size_t)(jb + jj) * T + tb + tt];
  }
  __syncthreads();
  for (int i = threadIdx.x; i < 4096; i += 256) {
    const int tt = i >> 6, jj = i & 63;
    Ex[(size_t)(tb + tt) * 1024 + jb + jj] = tile[jj][tt];
  }
}

// ---------------------------------------------------------------------------
// prep_A0: row 0 = exact alpha_0 (unnormalized) = exp(start)*E_0; rows>=1 = 1.0
// ---------------------------------------------------------------------------
__global__ void prep_A0(const float* __restrict__ start, const float* __restrict__ Ex,
                        __hip_bfloat16* __restrict__ A0) {
  const int idx = blockIdx.x * 256 + threadIdx.x;
  const int r = idx >> 10, j = idx & 1023;
  const float v = (r == 0) ? __expf(start[j]) * Ex[j] : 1.0f;
  A0[idx] = __float2bfloat16(v);
}

// ---------------------------------------------------------------------------
// stage one 128-k block of the WG's 32 A-rows into LDS [q][row][32 kw].
// ---------------------------------------------------------------------------
__device__ __forceinline__ void stage_rows(const __hip_bfloat16* __restrict__ Acur,
                                           __hip_bfloat16 (*buf)[ROWS][32],
                                           int m0, int kb, int tid) {
#pragma unroll
  for (int it = 0; it < 2; ++it) {
    const int idx = it * 256 + tid;  // 0..511
    const int q = idx >> 7, row = (idx >> 2) & 31, seg = idx & 3;
    *(int4v*)&buf[q][row][seg * 8] =
        *(const int4v*)(Acur + (size_t)(m0 + row) * 1024 + kb * 128 + q * 32 + seg * 8);
  }
}

// ---------------------------------------------------------------------------
// one recurrence step:  A_next = (A_cur @ P) .* E  * 2^15
// grid (16 ngroups, C/ROWS mgroups), 256 threads (4 waves), 2 WG/CU.
// B-fragments for the wave's 16-col panel preloaded into 128 VGPRs, reused
// across all 8 k-blocks -> inner loop is pure ds_read + MFMA.
// ---------------------------------------------------------------------------
__global__ __launch_bounds__(256, 2) void hmm_step(
    const __hip_bfloat16* __restrict__ Acur, __hip_bfloat16* __restrict__ Anext,
    const __hip_bfloat16* __restrict__ Pt, const float* __restrict__ Ex,
    float* __restrict__ Spart, int s) {
  __shared__ __align__(16) __hip_bfloat16 Astage[2][4][ROWS][32];
  __shared__ float sred[4][ROWS];
  const int tid = threadIdx.x;
  const int w = tid >> 6;
  const int l = tid & 63;
  const int ng = blockIdx.x;
  const int mg = blockIdx.y;
  const int m0 = mg * ROWS;
  const int n0 = ng << 6;
  const int ntw = (ng << 2) + w;

  // preload all B-frags for this wave's col-tile (32 x bf16x8 = 128 VGPRs)
  bf16x8 bf[32];
  const __hip_bfloat16* bbase =
      Pt + (size_t)ntw * 32 * 512 + (l & 15) * 32 + (l >> 4) * 8;
#pragma unroll
  for (int kc = 0; kc < 32; ++kc) bf[kc] = *(const bf16x8*)(bbase + kc * 512);

  f32x4 acc[2];
#pragma unroll
  for (int rt = 0; rt < 2; ++rt)
#pragma unroll
    for (int jj = 0; jj < 4; ++jj) acc[rt][jj] = 0.0f;

  stage_rows(Acur, Astage[0], m0, 0, tid);
  __syncthreads();

#pragma unroll
  for (int kb = 0; kb < 8; ++kb) {
    const int buf = kb & 1;
    if (kb < 7) stage_rows(Acur, Astage[buf ^ 1], m0, kb + 1, tid);
#pragma unroll
    for (int q = 0; q < 4; ++q) {
#pragma unroll
      for (int rt = 0; rt < 2; ++rt) {
        const bf16x8 afrag =
            *(const bf16x8*)&Astage[buf][q][rt * 16 + (l & 15)][(l >> 4) * 8];
        acc[rt] = __builtin_amdgcn_mfma_f32_16x16x32_bf16(afrag, bf[kb * 4 + q],
                                                          acc[rt], 0, 0, 0);
      }
    }
    __syncthreads();
  }

  // elementwise: emission scale, 2^15 rescale, bf16 writeback, row partial sums
  const int n = n0 + (w << 4) + (l & 15);
#pragma unroll
  for (int rt = 0; rt < 2; ++rt) {
#pragma unroll
    for (int j = 0; j < 4; ++j) {
      const int rl = rt * 16 + ((l >> 4) << 2) + j;
      const int r = m0 + rl;
      int t = (r == 0) ? (s - WARM) : (r * LCH - 1 - WARM + s);
      if (t < 0) t = 0;
      float outv;
      if ((r > 0) || (s > WARM))
        outv = acc[rt][j] * Ex[(size_t)t * 1024 + n] * 32768.0f;
      else
        outv = __bfloat162float(Acur[n]);  // chunk 0 frozen during warmup
      Anext[(size_t)r * 1024 + n] = __float2bfloat16(outv);
      float ssum = outv;
      ssum += __shfl_xor(ssum, 1);
      ssum += __shfl_xor(ssum, 2);
      ssum += __shfl_xor(ssum, 4);
      ssum += __shfl_xor(ssum, 8);
      if ((l & 15) == 0) sred[w][rl] = ssum;
    }
  }
  __syncthreads();
  if (s >= WARM && tid < ROWS) {
    const float tot = sred[0][tid] + sred[1][tid] + sred[2][tid] + sred[3][tid];
    Spart[((size_t)(m0 + tid) * (LCH + 1) + (s - WARM)) * 16 + ng] = tot;
  }
}

// ---------------------------------------------------------------------------
// final: Z_t from log-ratios of consecutive scaled sums.
// ---------------------------------------------------------------------------
__global__ void hmm_final(const float* __restrict__ Spart, float* __restrict__ out,
                          int T) {
  const int t = blockIdx.x * 256 + threadIdx.x;
  if (t >= T) return;
  const float C15 = 10.397207708399179f;  // 15*ln2
  auto S = [&](int c, int k) {
    const float* p = Spart + ((size_t)c * (LCH + 1) + k) * 16;
    float acc = 0.f;
#pragma unroll
    for (int g = 0; g < 16; ++g) acc += p[g];
    return acc;
  };
  float z;
  if (t == 0)
    z = logf(S(0, 0));
  else if (t < LCH)
    z = logf(S(0, t)) - logf(S(0, t - 1)) - C15;
  else {
    const int c = t >> 2, e = t & 3;
    z = logf(S(c, e + 1)) - logf(S(c, e)) - C15;
  }
  out[t] = z;
}

// ---------------------------------------------------------------------------
extern "C" void kernel_launch(void* const* d_in, const int* in_sizes, int n_in,
                              void* d_out, int out_size, void* d_ws, size_t ws_size,
                              hipStream_t stream) {
  const int* xs = (const int*)d_in[0];
  const float* start = (const float*)d_in[1];
  const float* trans = (const float*)d_in[2];
  const float* emit = (const float*)d_in[3];
  float* out = (float*)d_out;
  const int T = out_size;            // 4096
  const int V = in_sizes[3] >> 10;   // 32000
  const int C = T / LCH;             // 1024 chunks

  char* ws = (char*)d_ws;
  __hip_bfloat16* Pt = (__hip_bfloat16*)ws;                  // 2 MB @ 0
  float* Ex          = (float*)(ws + (2u << 20));            // 16 MB @ 2
  float* ExT         = (float*)(ws + (18u << 20));           // 16 MB @ 18 (dead after prep_tr)
  __hip_bfloat16* A0 = (__hip_bfloat16*)(ws + (18u << 20));  // 2 MB (reuses ExT space)
  __hip_bfloat16* A1 = (__hip_bfloat16*)(ws + (20u << 20));  // 2 MB
  float* Spart       = (float*)(ws + (22u << 20));           // 320 KB

  prep_Pt<<<dim3(512), dim3(256), 0, stream>>>(trans, Pt);
  prep_gather<<<dim3(1024), dim3(256), 0, stream>>>(emit, xs, ExT, V, T);
  prep_tr<<<dim3(T >> 6, 16), dim3(256), 0, stream>>>(ExT, Ex, T);
  prep_A0<<<dim3(C * 4), dim3(256), 0, stream>>>(start, Ex, A0);
  for (int s = 1; s <= NSTEP; ++s) {
    const __hip_bfloat16* ain = (s & 1) ? A0 : A1;
    __hip_bfloat16* aout = (s & 1) ? A1 : A0;
    hmm_step<<<dim3(16, C / ROWS), dim3(256), 0, stream>>>(ain, aout, Pt, Ex, Spart, s);
  }
  hmm_final<<<dim3((T + 255) / 256), dim3(256), 0, stream>>>(Spart, out, T);
}

// Round 3
// 198.482 us; speedup vs baseline: 2.0333x; 1.1302x over previous
//
#include <hip/hip_runtime.h>
#include <hip/hip_bf16.h>

typedef __attribute__((ext_vector_type(4))) float f32x4;
typedef __attribute__((ext_vector_type(8))) short bf16x8;
typedef __attribute__((ext_vector_type(4))) float float4v;

#define LCH 4        // timesteps emitted per chunk
#define WARM 4       // warmup steps (mixing ~0.009/step -> ~1e-8 residual)
#define NSTEP (WARM + LCH)

// ---------------------------------------------------------------------------
// prep_Pt: P transposed + tiled for coalesced MFMA B-fragment loads.
// Pt[(nt*32+kc)*512 + nw*32 + kw] = exp(trans[(kc*32+kw)*1024 + nt*16+nw])
// ---------------------------------------------------------------------------
__global__ void prep_Pt(const float* __restrict__ trans,
                        __hip_bfloat16* __restrict__ Pt) {
  __shared__ float l[4 * 544];
  const int nt = blockIdx.x >> 3;
  const int kc0 = (blockIdx.x & 7) << 2;
  for (int e = threadIdx.x; e < 2048; e += 256) {
    const int kcl = e >> 9, kw = (e >> 4) & 31, nw = e & 15;
    l[kcl * 544 + kw * 17 + nw] =
        __expf(trans[(size_t)((kc0 + kcl) * 32 + kw) * 1024 + nt * 16 + nw]);
  }
  __syncthreads();
  for (int o = threadIdx.x; o < 2048; o += 256) {
    const int kw = o & 31, nw = (o >> 5) & 15, kcl = o >> 9;
    Pt[(size_t)(nt * 32 + kc0 + kcl) * 512 + nw * 32 + kw] =
        __float2bfloat16(l[kcl * 544 + kw * 17 + nw]);
  }
}

// ---------------------------------------------------------------------------
// prep_gather: ExT[j][t] = bf16(exp(emit[j][xs[t]])). 2 blocks per row j;
// each stages half the row (62.5 KB) into LDS with streamed float4 loads
// (each emit line fetched exactly once -> ~131 MB HBM total), then gathers
// from LDS, predicated on which half owns xs[t].
// ---------------------------------------------------------------------------
__global__ __launch_bounds__(256) void prep_gather(
    const float* __restrict__ emit, const int* __restrict__ xs,
    __hip_bfloat16* __restrict__ ExT, int V, int T) {
  __shared__ float rowbuf[16000];  // 62.5 KB -> 2 WG/CU
  const int j = blockIdx.x >> 1;
  const int h = blockIdx.x & 1;
  const int VH = 16000;
  const int lo = h * VH;
  const int len = min(VH, V - lo);
  const float* row = emit + (size_t)j * V + lo;
  const int nv4 = len >> 2;
  for (int i = threadIdx.x; i < nv4; i += 256)
    ((float4v*)rowbuf)[i] = ((const float4v*)row)[i];
  for (int i = (nv4 << 2) + threadIdx.x; i < len; i += 256) rowbuf[i] = row[i];
  __syncthreads();
  __hip_bfloat16* orow = ExT + (size_t)j * T;
  for (int t = threadIdx.x; t < T; t += 256) {
    const int x = xs[t] - lo;
    if ((unsigned)x < (unsigned)len)
      orow[t] = __float2bfloat16(__expf(rowbuf[x]));
  }
}

// ---------------------------------------------------------------------------
// prep_tr: Ex[t][j] = ExT[j][t] via 64x64 LDS tiles (bf16 both sides).
// ---------------------------------------------------------------------------
__global__ void prep_tr(const __hip_bfloat16* __restrict__ ExT,
                        __hip_bfloat16* __restrict__ Ex, int T) {
  __shared__ __hip_bfloat16 tile[64][65];
  const int tb = blockIdx.x << 6, jb = blockIdx.y << 6;
  for (int i = threadIdx.x; i < 4096; i += 256) {
    const int jj = i >> 6, tt = i & 63;
    tile[jj][tt] = ExT[(size_t)(jb + jj) * T + tb + tt];
  }
  __syncthreads();
  for (int i = threadIdx.x; i < 4096; i += 256) {
    const int tt = i >> 6, jj = i & 63;
    Ex[(size_t)(tb + tt) * 1024 + jb + jj] = tile[jj][tt];
  }
}

// ---------------------------------------------------------------------------
// prep_A0: row 0 = exact alpha_0 = exp(start)*E_0; rows>=1 = 1.0
// ---------------------------------------------------------------------------
__global__ void prep_A0(const float* __restrict__ start,
                        const __hip_bfloat16* __restrict__ Ex,
                        __hip_bfloat16* __restrict__ A0) {
  const int idx = blockIdx.x * 256 + threadIdx.x;
  const int r = idx >> 10, j = idx & 1023;
  const float v = (r == 0) ? __expf(start[j]) * __bfloat162float(Ex[j]) : 1.0f;
  A0[idx] = __float2bfloat16(v);
}

__device__ __forceinline__ void gload_lds16(const void* g, void* l) {
  __builtin_amdgcn_global_load_lds((const __attribute__((address_space(1))) void*)g,
                                   (__attribute__((address_space(3))) void*)l,
                                   16, 0, 0);
}

// ---------------------------------------------------------------------------
// one recurrence step:  A_next = (A_cur @ P) .* E  * 2^15
// grid (16 ng, 16 mg) = 256 WGs (1/CU), 256 threads (4 waves).
// WG tile: 64 rows x 64 cols; wave w -> col-tile ntw = ng*4+w.
// A panel (64 rows x 1024 k) staged ONCE in MFMA-fragment order via
// global_load_lds (linear lane-order -> conflict-free ds_read_b128),
// all 32 B-frags preloaded in 128 VGPRs. One barrier, then 128 MFMA/wave.
// ---------------------------------------------------------------------------
__global__ __launch_bounds__(256) void hmm_step(
    const __hip_bfloat16* __restrict__ Acur, __hip_bfloat16* __restrict__ Anext,
    const __hip_bfloat16* __restrict__ Pt, const __hip_bfloat16* __restrict__ Ex,
    float* __restrict__ Spart, int s) {
  __shared__ __align__(16) __hip_bfloat16 Albs[128 * 512];  // 128 KB
  __shared__ float sred[4][64];
  const int tid = threadIdx.x;
  const int w = tid >> 6;
  const int l = tid & 63;
  const int ng = blockIdx.x;
  const int mg = blockIdx.y;
  const int m0 = mg << 6;
  const int n0 = ng << 6;
  const int ntw = (ng << 2) + w;

  // B-frag preload: 32 x bf16x8 = 128 VGPRs (this wave's 16-col panel, all k)
  bf16x8 bf[32];
  const __hip_bfloat16* bbase =
      Pt + (size_t)ntw * 32 * 512 + (l & 15) * 32 + (l >> 4) * 8;
#pragma unroll
  for (int kc = 0; kc < 32; ++kc) bf[kc] = *(const bf16x8*)(bbase + kc * 512);

  // A stage in fragment order: chunk c=(kc*4+rt), lane l holds its own frag.
#pragma unroll
  for (int i = 0; i < 32; ++i) {
    const int c = (w << 5) + i;
    const int kc = c >> 2, rt = c & 3;
    const __hip_bfloat16* gp = Acur + (size_t)(m0 + rt * 16 + (l & 15)) * 1024 +
                               kc * 32 + (l >> 4) * 8;
    gload_lds16(gp, Albs + (size_t)c * 512);
  }

  f32x4 acc[4];
#pragma unroll
  for (int rt = 0; rt < 4; ++rt)
#pragma unroll
    for (int jj = 0; jj < 4; ++jj) acc[rt][jj] = 0.0f;

  __syncthreads();

#pragma unroll
  for (int kc = 0; kc < 32; ++kc) {
#pragma unroll
    for (int rt = 0; rt < 4; ++rt) {
      const bf16x8 af = *(const bf16x8*)(Albs + (kc * 4 + rt) * 512 + l * 8);
      acc[rt] = __builtin_amdgcn_mfma_f32_16x16x32_bf16(af, bf[kc], acc[rt], 0, 0, 0);
    }
  }

  // epilogue: emission scale, 2^15 rescale, bf16 writeback, row partial sums
  const int n = n0 + (w << 4) + (l & 15);
#pragma unroll
  for (int rt = 0; rt < 4; ++rt) {
#pragma unroll
    for (int j = 0; j < 4; ++j) {
      const int rl = rt * 16 + ((l >> 4) << 2) + j;
      const int r = m0 + rl;
      int t = (r == 0) ? (s - WARM) : (r * LCH - 1 - WARM + s);
      if (t < 0) t = 0;
      float outv;
      if ((r > 0) || (s > WARM))
        outv = acc[rt][j] * __bfloat162float(Ex[(size_t)t * 1024 + n]) * 32768.0f;
      else
        outv = __bfloat162float(Acur[n]);  // chunk 0 frozen during warmup
      Anext[(size_t)r * 1024 + n] = __float2bfloat16(outv);
      float ssum = outv;
      ssum += __shfl_xor(ssum, 1);
      ssum += __shfl_xor(ssum, 2);
      ssum += __shfl_xor(ssum, 4);
      ssum += __shfl_xor(ssum, 8);
      if ((l & 15) == 0) sred[w][rl] = ssum;
    }
  }
  __syncthreads();
  if (s >= WARM && tid < 64) {
    const float tot = sred[0][tid] + sred[1][tid] + sred[2][tid] + sred[3][tid];
    Spart[((size_t)(m0 + tid) * (LCH + 1) + (s - WARM)) * 16 + ng] = tot;
  }
}

// ---------------------------------------------------------------------------
// final: Z_t from log-ratios of consecutive scaled sums.
// ---------------------------------------------------------------------------
__global__ void hmm_final(const float* __restrict__ Spart, float* __restrict__ out,
                          int T) {
  const int t = blockIdx.x * 256 + threadIdx.x;
  if (t >= T) return;
  const float C15 = 10.397207708399179f;  // 15*ln2
  auto S = [&](int c, int k) {
    const float* p = Spart + ((size_t)c * (LCH + 1) + k) * 16;
    float acc = 0.f;
#pragma unroll
    for (int g = 0; g < 16; ++g) acc += p[g];
    return acc;
  };
  float z;
  if (t == 0)
    z = logf(S(0, 0));
  else if (t < LCH)
    z = logf(S(0, t)) - logf(S(0, t - 1)) - C15;
  else {
    const int c = t >> 2, e = t & 3;
    z = logf(S(c, e + 1)) - logf(S(c, e)) - C15;
  }
  out[t] = z;
}

// ---------------------------------------------------------------------------
extern "C" void kernel_launch(void* const* d_in, const int* in_sizes, int n_in,
                              void* d_out, int out_size, void* d_ws, size_t ws_size,
                              hipStream_t stream) {
  const int* xs = (const int*)d_in[0];
  const float* start = (const float*)d_in[1];
  const float* trans = (const float*)d_in[2];
  const float* emit = (const float*)d_in[3];
  float* out = (float*)d_out;
  const int T = out_size;            // 4096
  const int K = in_sizes[1];         // 1024
  const int V = in_sizes[3] / K;     // 32000
  const int C = T / LCH;             // 1024 chunks

  char* ws = (char*)d_ws;
  __hip_bfloat16* Pt  = (__hip_bfloat16*)ws;                  // 2 MB @ 0
  __hip_bfloat16* ExT = (__hip_bfloat16*)(ws + (2u << 20));   // 8 MB @ 2
  __hip_bfloat16* Ex  = (__hip_bfloat16*)(ws + (10u << 20));  // 8 MB @ 10
  __hip_bfloat16* A0  = (__hip_bfloat16*)(ws + (18u << 20));  // 2 MB @ 18
  __hip_bfloat16* A1  = (__hip_bfloat16*)(ws + (20u << 20));  // 2 MB @ 20
  float* Spart        = (float*)(ws + (22u << 20));           // 320 KB @ 22

  prep_Pt<<<dim3(512), dim3(256), 0, stream>>>(trans, Pt);
  prep_gather<<<dim3(K * 2), dim3(256), 0, stream>>>(emit, xs, ExT, V, T);
  prep_tr<<<dim3(T >> 6, 16), dim3(256), 0, stream>>>(ExT, Ex, T);
  prep_A0<<<dim3(C * 4), dim3(256), 0, stream>>>(start, Ex, A0);
  for (int s = 1; s <= NSTEP; ++s) {
    const __hip_bfloat16* ain = (s & 1) ? A0 : A1;
    __hip_bfloat16* aout = (s & 1) ? A1 : A0;
    hmm_step<<<dim3(16, 16), dim3(256), 0, stream>>>(ain, aout, Pt, Ex, Spart, s);
  }
  hmm_final<<<dim3((T + 255) / 256), dim3(256), 0, stream>>>(Spart, out, T);
}